// Round 3
// baseline (438.455 us; speedup 1.0000x reference)
//
#include <hip/hip_runtime.h>

#define EMB   1024
#define SEQ   2048
#define BATCH 4
#define HEADS 16
#define HDIM  64
#define MTOT  8192

typedef __bf16 bf16x8 __attribute__((ext_vector_type(8)));
typedef float  fx4    __attribute__((ext_vector_type(4)));

#if __has_builtin(__builtin_amdgcn_exp2f)
#define EXP2(x) __builtin_amdgcn_exp2f(x)
#else
#define EXP2(x) exp2f(x)
#endif

__device__ __forceinline__ unsigned short f2bf(float f) {
    unsigned u = __builtin_bit_cast(unsigned, f);
    u += 0x7fffu + ((u >> 16) & 1u);   // RNE
    return (unsigned short)(u >> 16);
}
__device__ __forceinline__ unsigned short bfbits(float f) {
    __bf16 h = (__bf16)f;
    return __builtin_bit_cast(unsigned short, h);
}

#define AS1 __attribute__((address_space(1)))
#define AS3 __attribute__((address_space(3)))
__device__ __forceinline__ void glds16(const void* g, void* l) {
    __builtin_amdgcn_global_load_lds((AS1 void*)g, (AS3 void*)l, 16, 0, 0);
}

// log2(e)/32 — folded into Q so softmax is exp2(s) with no further scaling.
#define QSCALE 0.0450842137604569f

// ---------------------------------------------------------------------------
// x [8192x1024] fp32 -> bf16
// ---------------------------------------------------------------------------
__global__ __launch_bounds__(256) void cvt_x_kernel(const float* __restrict__ x,
                                                    unsigned short* __restrict__ xb)
{
    const int idx = (blockIdx.x * 256 + threadIdx.x) * 4;
    const float4 v = *(const float4*)(x + idx);
    ushort4 o;
    o.x = f2bf(v.x); o.y = f2bf(v.y); o.z = f2bf(v.z); o.w = f2bf(v.w);
    *(ushort4*)(xb + idx) = o;
}

// ---------------------------------------------------------------------------
// W [K][N] fp32 -> Wt [N][K] bf16 (transpose), 4 matrices via grid.z
// ---------------------------------------------------------------------------
__global__ __launch_bounds__(256) void cvt_w_kernel(
    const float* __restrict__ w0, const float* __restrict__ w1,
    const float* __restrict__ w2, const float* __restrict__ w3,
    unsigned short* __restrict__ o0, unsigned short* __restrict__ o1,
    unsigned short* __restrict__ o2, unsigned short* __restrict__ o3)
{
    const int z = blockIdx.z;
    const float* W = z == 0 ? w0 : (z == 1 ? w1 : (z == 2 ? w2 : w3));
    unsigned short* O = z == 0 ? o0 : (z == 1 ? o1 : (z == 2 ? o2 : o3));

    __shared__ float Ws[64][65];
    const int t  = threadIdx.x;
    const int k0 = blockIdx.x * 64, n0 = blockIdx.y * 64;
#pragma unroll
    for (int p = 0; p < 4; ++p) {
        const int row = p * 16 + (t >> 4);
        const int col = (t & 15) * 4;
        const float4 v = *(const float4*)(W + (size_t)(k0 + row) * EMB + n0 + col);
        Ws[row][col]     = v.x; Ws[row][col + 1] = v.y;
        Ws[row][col + 2] = v.z; Ws[row][col + 3] = v.w;
    }
    __syncthreads();
    const int nn = t >> 2;
    const int kb = (t & 3) * 16;
#pragma unroll
    for (int q = 0; q < 2; ++q) {
        const int kk = kb + q * 8;
        ushort4 u0, u1;
        u0.x = f2bf(Ws[kk + 0][nn]); u0.y = f2bf(Ws[kk + 1][nn]);
        u0.z = f2bf(Ws[kk + 2][nn]); u0.w = f2bf(Ws[kk + 3][nn]);
        u1.x = f2bf(Ws[kk + 4][nn]); u1.y = f2bf(Ws[kk + 5][nn]);
        u1.z = f2bf(Ws[kk + 6][nn]); u1.w = f2bf(Ws[kk + 7][nn]);
        *(ushort4*)(O + (size_t)(n0 + nn) * EMB + k0 + kk)     = u0;
        *(ushort4*)(O + (size_t)(n0 + nn) * EMB + k0 + kk + 4) = u1;
    }
}

// ---------------------------------------------------------------------------
// bf16 MFMA GEMM (m97 structure). mode 0: z= Q/K/V.
//   Q -> [B,H,N,D] bf16, scaled by QSCALE.
//   K -> [B,H,N,D] bf16.
//   V -> [B,H,D,N] bf16 with kv permuted within 64-blocks: pos=(n%16)*4+(n/16)%4
// mode 1: fp32 out [M][E].
// ---------------------------------------------------------------------------
__global__ __launch_bounds__(256) void gemm_bf16_kernel(
    const unsigned short* __restrict__ Ag,
    const unsigned short* __restrict__ B0, const unsigned short* __restrict__ B1,
    const unsigned short* __restrict__ B2,
    const float* __restrict__ bias0, const float* __restrict__ bias1,
    const float* __restrict__ bias2,
    void* out0, void* out1, void* out2, int mode)
{
    const int z = blockIdx.z;
    const unsigned short* __restrict__ Bg = z == 0 ? B0 : (z == 1 ? B1 : B2);
    const float* __restrict__ bias = z == 0 ? bias0 : (z == 1 ? bias1 : bias2);
    void* outp = z == 0 ? out0 : (z == 1 ? out1 : out2);

    __shared__ unsigned short As[128][32];
    __shared__ unsigned short Bs[128][32];

    const int t    = threadIdx.x;
    const int w    = t >> 6;
    const int lane = t & 63;
    const int low4 = lane & 15;
    const int quad = lane >> 4;
    const int m0 = blockIdx.x * 128;
    const int e0 = blockIdx.y * 128;
    const int wr = (w & 1) * 64;
    const int wc = (w >> 1) * 64;

    const int srow = w * 32 + (lane >> 2);
    const int scol = (lane & 3) * 8;

    fx4 acc[4][4] = {};

    for (int k0 = 0; k0 < EMB; k0 += 32) {
        __syncthreads();
        glds16(Ag + (size_t)(m0 + srow) * EMB + k0 + scol,      &As[w * 32][0]);
        glds16(Ag + (size_t)(m0 + srow + 16) * EMB + k0 + scol, &As[w * 32 + 16][0]);
        glds16(Bg + (size_t)(e0 + srow) * EMB + k0 + scol,      &Bs[w * 32][0]);
        glds16(Bg + (size_t)(e0 + srow + 16) * EMB + k0 + scol, &Bs[w * 32 + 16][0]);
        __syncthreads();

        bf16x8 af[4], bfr[4];
#pragma unroll
        for (int i = 0; i < 4; ++i) {
            af[i]  = *(const bf16x8*)&As[wr + i * 16 + low4][quad * 8];
            bfr[i] = *(const bf16x8*)&Bs[wc + i * 16 + low4][quad * 8];
        }
#pragma unroll
        for (int i = 0; i < 4; ++i)
#pragma unroll
            for (int j = 0; j < 4; ++j)
                acc[i][j] = __builtin_amdgcn_mfma_f32_16x16x32_bf16(af[i], bfr[j], acc[i][j], 0, 0, 0);
    }

    float bv[4];
#pragma unroll
    for (int j = 0; j < 4; ++j) bv[j] = bias[e0 + wc + j * 16 + low4];

#pragma unroll
    for (int i = 0; i < 4; ++i) {
#pragma unroll
        for (int j = 0; j < 4; ++j) {
#pragma unroll
            for (int rr = 0; rr < 4; ++rr) {
                const int m = m0 + wr + i * 16 + quad * 4 + rr;
                const int e = e0 + wc + j * 16 + low4;
                float val = acc[i][j][rr] + bv[j];
                if (mode == 1) {
                    ((float*)outp)[(size_t)m * EMB + e] = val;
                } else {
                    const int bb = m >> 11, n = m & (SEQ - 1);
                    const int hh = e >> 6, d = e & 63;
                    unsigned short* o = (unsigned short*)outp;
                    if (z == 0) {
                        val *= QSCALE;
                        o[(((size_t)(bb * HEADS + hh)) * SEQ + n) * HDIM + d] = f2bf(val);
                    } else if (z == 1) {
                        o[(((size_t)(bb * HEADS + hh)) * SEQ + n) * HDIM + d] = f2bf(val);
                    } else {
                        // V transposed + kv-permuted within 64-blocks
                        const int nl = n & 63;
                        const int np = (n & ~63) | (((nl & 15) << 2) | (nl >> 4));
                        o[(((size_t)(bb * HEADS + hh)) * HDIM + d) * SEQ + np] = f2bf(val);
                    }
                }
            }
        }
    }
}

// ---------------------------------------------------------------------------
// MFMA flash attention v2: no-max softmax (exp2, scale pre-folded into Q),
// K/V fragments direct from global (no barriers), P via per-wave LDS (b64
// stores with kv-permuted layout matching V's permutation).
// Block = 256 thr = 4 waves; wave owns 32 q-rows. Grid (SEQ/128, B*H).
// ---------------------------------------------------------------------------
__global__ __launch_bounds__(256) void attn_mfma2_kernel(
    const unsigned short* __restrict__ qg, const unsigned short* __restrict__ kg,
    const unsigned short* __restrict__ vg, unsigned short* __restrict__ attb)
{
    __shared__ unsigned short Ps[4][32][72];   // per-wave P [q][kv'], stride 72

    const int t    = threadIdx.x;
    const int w    = t >> 6;
    const int lane = t & 63;
    const int low4 = lane & 15;
    const int quad = lane >> 4;
    const int q0   = blockIdx.x * 128 + w * 32;
    const int bh   = blockIdx.y;
    const size_t base = (size_t)bh * SEQ * HDIM;

    // resident Q A-fragments: 2 sub-tiles of 16 q-rows
    bf16x8 aq[2][2];
#pragma unroll
    for (int s = 0; s < 2; ++s) {
        const size_t qrow = base + (size_t)(q0 + s * 16 + low4) * HDIM;
        aq[s][0] = *(const bf16x8*)(qg + qrow + quad * 8);
        aq[s][1] = *(const bf16x8*)(qg + qrow + 32 + quad * 8);
    }

    fx4 o_acc[2][4] = {};
    float l_i[2][4] = {};
    const fx4 fzero = {0.f, 0.f, 0.f, 0.f};

    for (int kv0 = 0; kv0 < SEQ; kv0 += 64) {
        // K fragments from global: B[k=d][n=kv] <- K[kv0+tt*16+low4][d]
        bf16x8 kf[4][2], vf[4][2];
#pragma unroll
        for (int tt = 0; tt < 4; ++tt) {
            const size_t krow = base + (size_t)(kv0 + tt * 16 + low4) * HDIM;
            kf[tt][0] = *(const bf16x8*)(kg + krow + quad * 8);
            kf[tt][1] = *(const bf16x8*)(kg + krow + 32 + quad * 8);
        }
        // V fragments from global: B[k'=kv'][n=d] <- V^T[d][kv0 + kv'] (permuted)
#pragma unroll
        for (int t2 = 0; t2 < 4; ++t2) {
            const size_t vrow = base + (size_t)(t2 * 16 + low4) * SEQ + kv0;
            vf[t2][0] = *(const bf16x8*)(vg + vrow + quad * 8);
            vf[t2][1] = *(const bf16x8*)(vg + vrow + 32 + quad * 8);
        }

        // S = Q K^T, P = exp2(S), store P to LDS in kv' order
#pragma unroll
        for (int s = 0; s < 2; ++s) {
            fx4 sa[4];
#pragma unroll
            for (int tt = 0; tt < 4; ++tt) {
                sa[tt] = __builtin_amdgcn_mfma_f32_16x16x32_bf16(aq[s][0], kf[tt][0], fzero, 0, 0, 0);
                sa[tt] = __builtin_amdgcn_mfma_f32_16x16x32_bf16(aq[s][1], kf[tt][1], sa[tt], 0, 0, 0);
            }
#pragma unroll
            for (int r = 0; r < 4; ++r) {
                const float p0 = EXP2(sa[0][r]);
                const float p1 = EXP2(sa[1][r]);
                const float p2 = EXP2(sa[2][r]);
                const float p3 = EXP2(sa[3][r]);
                l_i[s][r] += (p0 + p1) + (p2 + p3);
                uint2 pk;
                pk.x = (unsigned)bfbits(p0) | ((unsigned)bfbits(p1) << 16);
                pk.y = (unsigned)bfbits(p2) | ((unsigned)bfbits(p3) << 16);
                // row q = s*16 + quad*4 + r, cols kv' = low4*4 .. +3
                *(uint2*)&Ps[w][s * 16 + quad * 4 + r][low4 * 4] = pk;
            }
        }

        // O += P V  (per-wave LDS, in-order DS — no barrier needed)
#pragma unroll
        for (int s = 0; s < 2; ++s) {
            bf16x8 pf0 = *(const bf16x8*)&Ps[w][s * 16 + low4][quad * 8];
            bf16x8 pf1 = *(const bf16x8*)&Ps[w][s * 16 + low4][32 + quad * 8];
#pragma unroll
            for (int t2 = 0; t2 < 4; ++t2) {
                o_acc[s][t2] = __builtin_amdgcn_mfma_f32_16x16x32_bf16(pf0, vf[t2][0], o_acc[s][t2], 0, 0, 0);
                o_acc[s][t2] = __builtin_amdgcn_mfma_f32_16x16x32_bf16(pf1, vf[t2][1], o_acc[s][t2], 0, 0, 0);
            }
        }
    }

    // final l reduction across the 16 lanes of each quad
#pragma unroll
    for (int s = 0; s < 2; ++s)
#pragma unroll
        for (int r = 0; r < 4; ++r) {
            float v = l_i[s][r];
            for (int off = 1; off < 16; off <<= 1)
                v += __shfl_xor(v, off, 16);
            l_i[s][r] = 1.0f / v;
        }

    // epilogue: merge heads -> att [B*N][EMB] bf16
    const int bb = bh >> 4, hh = bh & 15;
#pragma unroll
    for (int s = 0; s < 2; ++s)
#pragma unroll
        for (int r = 0; r < 4; ++r) {
            const size_t m = (size_t)bb * SEQ + q0 + s * 16 + quad * 4 + r;
#pragma unroll
            for (int t2 = 0; t2 < 4; ++t2) {
                const int e = hh * HDIM + t2 * 16 + low4;
                attb[m * EMB + e] = bfbits(o_acc[s][t2][r] * l_i[s][r]);
            }
        }
}

extern "C" void kernel_launch(void* const* d_in, const int* in_sizes, int n_in,
                              void* d_out, int out_size, void* d_ws, size_t ws_size,
                              hipStream_t stream)
{
    const float* x  = (const float*)d_in[0];
    const float* Wq = (const float*)d_in[1];
    const float* bq = (const float*)d_in[2];
    const float* Wk = (const float*)d_in[3];
    const float* bk = (const float*)d_in[4];
    const float* Wv = (const float*)d_in[5];
    const float* bv = (const float*)d_in[6];
    const float* Wo = (const float*)d_in[7];
    const float* bo = (const float*)d_in[8];

    unsigned short* ws  = (unsigned short*)d_ws;
    unsigned short* xb  = ws;                  // 8388608
    unsigned short* wqt = xb + 8388608;        // 1048576 each
    unsigned short* wkt = wqt + 1048576;
    unsigned short* wvt = wkt + 1048576;
    unsigned short* wot = wvt + 1048576;
    unsigned short* qb  = wot + 1048576;       // 8388608 each
    unsigned short* kbuf = qb + 8388608;
    unsigned short* vtb  = kbuf + 8388608;
    unsigned short* attb = vtb + 8388608;

    cvt_x_kernel<<<8192, 256, 0, stream>>>(x, xb);
    cvt_w_kernel<<<dim3(16, 16, 4), 256, 0, stream>>>(Wq, Wk, Wv, Wo, wqt, wkt, wvt, wot);

    gemm_bf16_kernel<<<dim3(64, 8, 3), 256, 0, stream>>>(
        xb, wqt, wkt, wvt, bq, bk, bv, qb, kbuf, vtb, 0);

    attn_mfma2_kernel<<<dim3(16, 64), 256, 0, stream>>>(qb, kbuf, vtb, attb);

    gemm_bf16_kernel<<<dim3(64, 8, 1), 256, 0, stream>>>(
        attb, wot, wot, wot, bo, bo, bo, d_out, d_out, d_out, 1);
}

// Round 5
// 291.523 us; speedup vs baseline: 1.5040x; 1.5040x over previous
//
#include <hip/hip_runtime.h>

#define EMB   1024
#define SEQ   2048
#define BATCH 4
#define HEADS 16
#define HDIM  64
#define MTOT  8192

typedef __bf16 bf16x8 __attribute__((ext_vector_type(8)));
typedef float  fx4    __attribute__((ext_vector_type(4)));

#if __has_builtin(__builtin_amdgcn_exp2f)
#define EXP2(x) __builtin_amdgcn_exp2f(x)
#else
#define EXP2(x) exp2f(x)
#endif

__device__ __forceinline__ unsigned short f2bf(float f) {
    unsigned u = __builtin_bit_cast(unsigned, f);
    u += 0x7fffu + ((u >> 16) & 1u);   // RNE
    return (unsigned short)(u >> 16);
}
__device__ __forceinline__ unsigned short bfbits(float f) {
    __bf16 h = (__bf16)f;
    return __builtin_bit_cast(unsigned short, h);
}

#define AS1 __attribute__((address_space(1)))
#define AS3 __attribute__((address_space(3)))
__device__ __forceinline__ void glds16(const void* g, void* l) {
    __builtin_amdgcn_global_load_lds((AS1 void*)g, (AS3 void*)l, 16, 0, 0);
}
// vmcnt(0), expcnt/lgkmcnt unconstrained (gfx9-family encoding 0x0f70).
// REQUIRED before the barrier that publishes global_load_lds data: the
// compiler does NOT reliably drain LDS-DMA vmcnt at s_barrier when the glds
// is issued far upstream (round-4 failure: correct cold, stale-read warm).
#define DRAIN_GLDS() __builtin_amdgcn_s_waitcnt(0x0f70)

// log2(e)/32 — folded into Q so softmax is exp2(s) with no further scaling.
#define QSCALE 0.0450842137604569f

// ---------------------------------------------------------------------------
// x [8192x1024] fp32 -> bf16
// ---------------------------------------------------------------------------
__global__ __launch_bounds__(256) void cvt_x_kernel(const float* __restrict__ x,
                                                    unsigned short* __restrict__ xb)
{
    const int idx = (blockIdx.x * 256 + threadIdx.x) * 4;
    const float4 v = *(const float4*)(x + idx);
    ushort4 o;
    o.x = f2bf(v.x); o.y = f2bf(v.y); o.z = f2bf(v.z); o.w = f2bf(v.w);
    *(ushort4*)(xb + idx) = o;
}

// ---------------------------------------------------------------------------
// W [K][N] fp32 -> Wt [N][K] bf16 (transpose), 4 matrices via grid.z
// ---------------------------------------------------------------------------
__global__ __launch_bounds__(256) void cvt_w_kernel(
    const float* __restrict__ w0, const float* __restrict__ w1,
    const float* __restrict__ w2, const float* __restrict__ w3,
    unsigned short* __restrict__ o0, unsigned short* __restrict__ o1,
    unsigned short* __restrict__ o2, unsigned short* __restrict__ o3)
{
    const int z = blockIdx.z;
    const float* W = z == 0 ? w0 : (z == 1 ? w1 : (z == 2 ? w2 : w3));
    unsigned short* O = z == 0 ? o0 : (z == 1 ? o1 : (z == 2 ? o2 : o3));

    __shared__ float Ws[64][65];
    const int t  = threadIdx.x;
    const int k0 = blockIdx.x * 64, n0 = blockIdx.y * 64;
#pragma unroll
    for (int p = 0; p < 4; ++p) {
        const int row = p * 16 + (t >> 4);
        const int col = (t & 15) * 4;
        const float4 v = *(const float4*)(W + (size_t)(k0 + row) * EMB + n0 + col);
        Ws[row][col]     = v.x; Ws[row][col + 1] = v.y;
        Ws[row][col + 2] = v.z; Ws[row][col + 3] = v.w;
    }
    __syncthreads();
    const int nn = t >> 2;
    const int kb = (t & 3) * 16;
#pragma unroll
    for (int q = 0; q < 2; ++q) {
        const int kk = kb + q * 8;
        ushort4 u0, u1;
        u0.x = f2bf(Ws[kk + 0][nn]); u0.y = f2bf(Ws[kk + 1][nn]);
        u0.z = f2bf(Ws[kk + 2][nn]); u0.w = f2bf(Ws[kk + 3][nn]);
        u1.x = f2bf(Ws[kk + 4][nn]); u1.y = f2bf(Ws[kk + 5][nn]);
        u1.z = f2bf(Ws[kk + 6][nn]); u1.w = f2bf(Ws[kk + 7][nn]);
        *(ushort4*)(O + (size_t)(n0 + nn) * EMB + k0 + kk)     = u0;
        *(ushort4*)(O + (size_t)(n0 + nn) * EMB + k0 + kk + 4) = u1;
    }
}

// ---------------------------------------------------------------------------
// bf16 MFMA GEMM, A/B-swapped epilogue: A-operand = W rows (output cols e),
// B-operand = x rows (m). C^T layout: lane holds 4 CONSECUTIVE e per reg set
// -> vectorized stores (ushort4 for Q/K, float4 for mode 1).
// mode 0: z= Q/K/V. Q -> [B,H,N,D] bf16 * QSCALE; K -> [B,H,N,D];
//         V -> [B,H,D,N] bf16, kv permuted in 64-blocks: np=(n%16)*4+(n/16)%4
// mode 1: fp32 out [M][E].
// glds immediately precedes the consuming barrier (m97-proven shape).
// ---------------------------------------------------------------------------
__global__ __launch_bounds__(256) void gemm_bf16_kernel(
    const unsigned short* __restrict__ Ag,
    const unsigned short* __restrict__ B0, const unsigned short* __restrict__ B1,
    const unsigned short* __restrict__ B2,
    const float* __restrict__ bias0, const float* __restrict__ bias1,
    const float* __restrict__ bias2,
    void* out0, void* out1, void* out2, int mode)
{
    const int z = blockIdx.z;
    const unsigned short* __restrict__ Bg = z == 0 ? B0 : (z == 1 ? B1 : B2);
    const float* __restrict__ bias = z == 0 ? bias0 : (z == 1 ? bias1 : bias2);
    void* outp = z == 0 ? out0 : (z == 1 ? out1 : out2);

    __shared__ unsigned short As[128][32];   // x rows
    __shared__ unsigned short Bs[128][32];   // W rows (output cols)

    const int t    = threadIdx.x;
    const int w    = t >> 6;
    const int lane = t & 63;
    const int low4 = lane & 15;
    const int quad = lane >> 4;
    const int m0 = blockIdx.x * 128;
    const int e0 = blockIdx.y * 128;
    const int we = (w & 1) * 64;     // e-offset of this wave
    const int wm = (w >> 1) * 64;    // m-offset of this wave

    const int srow = w * 32 + (lane >> 2);
    const int scol = (lane & 3) * 8;

    fx4 acc[4][4] = {};   // [i: e-subtile][j: m-subtile]

    for (int k0 = 0; k0 < EMB; k0 += 32) {
        __syncthreads();
        glds16(Ag + (size_t)(m0 + srow) * EMB + k0 + scol,      &As[w * 32][0]);
        glds16(Ag + (size_t)(m0 + srow + 16) * EMB + k0 + scol, &As[w * 32 + 16][0]);
        glds16(Bg + (size_t)(e0 + srow) * EMB + k0 + scol,      &Bs[w * 32][0]);
        glds16(Bg + (size_t)(e0 + srow + 16) * EMB + k0 + scol, &Bs[w * 32 + 16][0]);
        DRAIN_GLDS();
        __syncthreads();

        bf16x8 af[4], bfr[4];
#pragma unroll
        for (int i = 0; i < 4; ++i) {
            af[i]  = *(const bf16x8*)&Bs[we + i * 16 + low4][quad * 8];  // A = W
            bfr[i] = *(const bf16x8*)&As[wm + i * 16 + low4][quad * 8];  // B = x
        }
#pragma unroll
        for (int i = 0; i < 4; ++i)
#pragma unroll
            for (int j = 0; j < 4; ++j)
                acc[i][j] = __builtin_amdgcn_mfma_f32_16x16x32_bf16(af[i], bfr[j], acc[i][j], 0, 0, 0);
    }

    // bias: e = e0 + we + i*16 + quad*4 + rr  (4 consecutive)
    fx4 bv[4];
#pragma unroll
    for (int i = 0; i < 4; ++i)
        bv[i] = *(const fx4*)(bias + e0 + we + i * 16 + quad * 4);

#pragma unroll
    for (int i = 0; i < 4; ++i) {
#pragma unroll
        for (int j = 0; j < 4; ++j) {
            const int m  = m0 + wm + j * 16 + low4;
            const int eb = e0 + we + i * 16 + quad * 4;
            if (mode == 1) {
                fx4 o4;
#pragma unroll
                for (int rr = 0; rr < 4; ++rr) o4[rr] = acc[i][j][rr] + bv[i][rr];
                *(fx4*)((float*)outp + (size_t)m * EMB + eb) = o4;
            } else {
                const int bb = m >> 11, n = m & (SEQ - 1);
                const int hh = eb >> 6, db = eb & 63;
                unsigned short* o = (unsigned short*)outp;
                if (z <= 1) {
                    const float sc = (z == 0) ? QSCALE : 1.0f;
                    ushort4 o4;
                    o4.x = f2bf((acc[i][j][0] + bv[i][0]) * sc);
                    o4.y = f2bf((acc[i][j][1] + bv[i][1]) * sc);
                    o4.z = f2bf((acc[i][j][2] + bv[i][2]) * sc);
                    o4.w = f2bf((acc[i][j][3] + bv[i][3]) * sc);
                    *(ushort4*)(o + (((size_t)(bb * HEADS + hh)) * SEQ + n) * HDIM + db) = o4;
                } else {
                    const int nl = n & 63;
                    const int np = (n & ~63) | (((nl & 15) << 2) | (nl >> 4));
#pragma unroll
                    for (int rr = 0; rr < 4; ++rr)
                        o[(((size_t)(bb * HEADS + hh)) * HDIM + db + rr) * SEQ + np] =
                            f2bf(acc[i][j][rr] + bv[i][rr]);
                }
            }
        }
    }
}

// ---------------------------------------------------------------------------
// MFMA flash attention v3b: LDS-staged K/V (glds16, double-buffered, one
// barrier per tile + EXPLICIT vmcnt(0) drain — the round-4 race fix), XOR
// chunk swizzle on staging source (conflict-free unpadded reads), no-max
// softmax (exp2, scale folded into Q), per-wave P round-trip.
// Wave = 64 q-rows; block = 4 waves = 256 q-rows. Grid (SEQ/256, B*H).
// Q,K: [B,H,N,D] bf16; V: [B,H,D,N] bf16 (kv permuted per 64-block).
// ---------------------------------------------------------------------------
__global__ __launch_bounds__(256, 2) void attn_mfma3_kernel(
    const unsigned short* __restrict__ qg, const unsigned short* __restrict__ kg,
    const unsigned short* __restrict__ vg, unsigned short* __restrict__ attb)
{
    __shared__ unsigned short Ks[2][64][64];   // [buf][kv][d], chunk-swizzled
    __shared__ unsigned short Vs[2][64][64];   // [buf][d][kv'], chunk-swizzled
    __shared__ unsigned short Ps[4][16][72];   // per-wave P [q][kv'], stride 72

    const int t    = threadIdx.x;
    const int w    = t >> 6;
    const int lane = t & 63;
    const int low4 = lane & 15;
    const int quad = lane >> 4;
    const int q0   = blockIdx.x * 256 + w * 64;
    const int bh   = blockIdx.y;
    const size_t base = (size_t)bh * SEQ * HDIM;

    // staging source (XOR swizzle): lane covers row srow8, global chunk schunk
    const int srow8  = lane >> 3;                    // 0..7 within 8-row group
    const int schunk = (lane & 7) ^ srow8;           // swizzled 16B chunk

    // resident Q A-fragments: 4 sub-tiles of 16 q-rows
    bf16x8 aq[4][2];
#pragma unroll
    for (int s = 0; s < 4; ++s) {
        const size_t qrow = base + (size_t)(q0 + s * 16 + low4) * HDIM;
        aq[s][0] = *(const bf16x8*)(qg + qrow + quad * 8);
        aq[s][1] = *(const bf16x8*)(qg + qrow + 32 + quad * 8);
    }

    fx4 o_acc[4][4] = {};
    float l_i[4][4] = {};
    const fx4 fzero = {0.f, 0.f, 0.f, 0.f};

    // prologue: stage tile 0 into buf 0
    {
        const unsigned short* kp = kg + base + (size_t)(w * 16 + srow8) * HDIM + schunk * 8;
        glds16(kp,              &Ks[0][w * 16][0]);
        glds16(kp + 8 * HDIM,   &Ks[0][w * 16 + 8][0]);
        const unsigned short* vp = vg + base + (size_t)(w * 16 + srow8) * SEQ + schunk * 8;
        glds16(vp,              &Vs[0][w * 16][0]);
        glds16(vp + 8 * SEQ,    &Vs[0][w * 16 + 8][0]);
    }

    for (int tt0 = 0; tt0 < SEQ / 64; ++tt0) {
        const int buf = tt0 & 1;
        DRAIN_GLDS();      // drain this wave's in-flight glds (round-4 fix)
        __syncthreads();   // rendezvous: all waves' DMA data now in LDS

        // K/V fragments -> registers (unswizzle: lds chunk = cg ^ (row&7))
        bf16x8 kf[4][2], vf[4][2];
#pragma unroll
        for (int tk = 0; tk < 4; ++tk) {
            const int row = tk * 16 + low4;
            const int x7  = low4 & 7;
#pragma unroll
            for (int c = 0; c < 2; ++c) {
                const int lc = (c * 4 + quad) ^ x7;
                kf[tk][c] = *(const bf16x8*)&Ks[buf][row][lc * 8];
                vf[tk][c] = *(const bf16x8*)&Vs[buf][row][lc * 8];
            }
        }

        // prefetch next tile into other buffer (overlaps compute below)
        if (tt0 + 1 < SEQ / 64) {
            const int kv1 = (tt0 + 1) * 64;
            const unsigned short* kp = kg + base + (size_t)(kv1 + w * 16 + srow8) * HDIM + schunk * 8;
            glds16(kp,            &Ks[buf ^ 1][w * 16][0]);
            glds16(kp + 8 * HDIM, &Ks[buf ^ 1][w * 16 + 8][0]);
            const unsigned short* vp = vg + base + (size_t)(w * 16 + srow8) * SEQ + kv1 + schunk * 8;
            glds16(vp,            &Vs[buf ^ 1][w * 16][0]);
            glds16(vp + 8 * SEQ,  &Vs[buf ^ 1][w * 16 + 8][0]);
        }

#pragma unroll
        for (int s = 0; s < 4; ++s) {
            // S = Q K^T
            fx4 sa[4];
#pragma unroll
            for (int tk = 0; tk < 4; ++tk) {
                sa[tk] = __builtin_amdgcn_mfma_f32_16x16x32_bf16(aq[s][0], kf[tk][0], fzero, 0, 0, 0);
                sa[tk] = __builtin_amdgcn_mfma_f32_16x16x32_bf16(aq[s][1], kf[tk][1], sa[tk], 0, 0, 0);
            }
            // P = exp2(S); store per-wave (kv' = low4*4 + tk matches V permute)
#pragma unroll
            for (int r = 0; r < 4; ++r) {
                const float p0 = EXP2(sa[0][r]);
                const float p1 = EXP2(sa[1][r]);
                const float p2 = EXP2(sa[2][r]);
                const float p3 = EXP2(sa[3][r]);
                l_i[s][r] += (p0 + p1) + (p2 + p3);
                uint2 pk;
                pk.x = (unsigned)bfbits(p0) | ((unsigned)bfbits(p1) << 16);
                pk.y = (unsigned)bfbits(p2) | ((unsigned)bfbits(p3) << 16);
                *(uint2*)&Ps[w][quad * 4 + r][low4 * 4] = pk;
            }
            // compiler ordering fence: P writes must precede P reads
            __asm__ volatile("" ::: "memory");
            // O += P V  (intra-wave LDS ordering, no barrier)
            bf16x8 pf0 = *(const bf16x8*)&Ps[w][low4][quad * 8];
            bf16x8 pf1 = *(const bf16x8*)&Ps[w][low4][32 + quad * 8];
#pragma unroll
            for (int t2 = 0; t2 < 4; ++t2) {
                o_acc[s][t2] = __builtin_amdgcn_mfma_f32_16x16x32_bf16(pf0, vf[t2][0], o_acc[s][t2], 0, 0, 0);
                o_acc[s][t2] = __builtin_amdgcn_mfma_f32_16x16x32_bf16(pf1, vf[t2][1], o_acc[s][t2], 0, 0, 0);
            }
        }
    }

    // final l reduction across the 16 lanes of each quad-row group
#pragma unroll
    for (int s = 0; s < 4; ++s)
#pragma unroll
        for (int r = 0; r < 4; ++r) {
            float v = l_i[s][r];
            for (int off = 1; off < 16; off <<= 1)
                v += __shfl_xor(v, off, 16);
            l_i[s][r] = 1.0f / v;
        }

    // epilogue: merge heads -> att [B*N][EMB] bf16
    const int bb = bh >> 4, hh = bh & 15;
#pragma unroll
    for (int s = 0; s < 4; ++s)
#pragma unroll
        for (int r = 0; r < 4; ++r) {
            const size_t m = (size_t)bb * SEQ + q0 + s * 16 + quad * 4 + r;
#pragma unroll
            for (int t2 = 0; t2 < 4; ++t2) {
                const int e = hh * HDIM + t2 * 16 + low4;
                attb[m * EMB + e] = bfbits(o_acc[s][t2][r] * l_i[s][r]);
            }
        }
}

extern "C" void kernel_launch(void* const* d_in, const int* in_sizes, int n_in,
                              void* d_out, int out_size, void* d_ws, size_t ws_size,
                              hipStream_t stream)
{
    const float* x  = (const float*)d_in[0];
    const float* Wq = (const float*)d_in[1];
    const float* bq = (const float*)d_in[2];
    const float* Wk = (const float*)d_in[3];
    const float* bk = (const float*)d_in[4];
    const float* Wv = (const float*)d_in[5];
    const float* bv = (const float*)d_in[6];
    const float* Wo = (const float*)d_in[7];
    const float* bo = (const float*)d_in[8];

    unsigned short* ws  = (unsigned short*)d_ws;
    unsigned short* xb  = ws;                  // 8388608
    unsigned short* wqt = xb + 8388608;        // 1048576 each
    unsigned short* wkt = wqt + 1048576;
    unsigned short* wvt = wkt + 1048576;
    unsigned short* wot = wvt + 1048576;
    unsigned short* qb  = wot + 1048576;       // 8388608 each
    unsigned short* kbuf = qb + 8388608;
    unsigned short* vtb  = kbuf + 8388608;
    unsigned short* attb = vtb + 8388608;

    cvt_x_kernel<<<8192, 256, 0, stream>>>(x, xb);
    cvt_w_kernel<<<dim3(16, 16, 4), 256, 0, stream>>>(Wq, Wk, Wv, Wo, wqt, wkt, wvt, wot);

    gemm_bf16_kernel<<<dim3(64, 8, 3), 256, 0, stream>>>(
        xb, wqt, wkt, wvt, bq, bk, bv, qb, kbuf, vtb, 0);

    attn_mfma3_kernel<<<dim3(8, 64), 256, 0, stream>>>(qb, kbuf, vtb, attb);

    gemm_bf16_kernel<<<dim3(64, 8, 1), 256, 0, stream>>>(
        attb, wot, wot, wot, bo, bo, bo, d_out, d_out, d_out, 1);
}

// Round 6
// 283.976 us; speedup vs baseline: 1.5440x; 1.0266x over previous
//
#include <hip/hip_runtime.h>

#define EMB   1024
#define SEQ   2048
#define BATCH 4
#define HEADS 16
#define HDIM  64
#define MTOT  8192

typedef __bf16 bf16x8 __attribute__((ext_vector_type(8)));
typedef float  fx4    __attribute__((ext_vector_type(4)));

#if __has_builtin(__builtin_amdgcn_exp2f)
#define EXP2(x) __builtin_amdgcn_exp2f(x)
#else
#define EXP2(x) exp2f(x)
#endif

__device__ __forceinline__ unsigned short f2bf(float f) {
    unsigned u = __builtin_bit_cast(unsigned, f);
    u += 0x7fffu + ((u >> 16) & 1u);   // RNE
    return (unsigned short)(u >> 16);
}
__device__ __forceinline__ unsigned short bfbits(float f) {
    __bf16 h = (__bf16)f;
    return __builtin_bit_cast(unsigned short, h);
}

#define AS1 __attribute__((address_space(1)))
#define AS3 __attribute__((address_space(3)))
__device__ __forceinline__ void glds16(const void* g, void* l) {
    __builtin_amdgcn_global_load_lds((AS1 void*)g, (AS3 void*)l, 16, 0, 0);
}
// vmcnt(0), expcnt/lgkmcnt unconstrained (gfx9 encoding). REQUIRED before the
// barrier that publishes global_load_lds data (round-4 race: compiler does not
// reliably drain LDS-DMA vmcnt at s_barrier when glds is issued far upstream).
#define DRAIN_GLDS() __builtin_amdgcn_s_waitcnt(0x0f70)

// log2(e)/32 — folded into Q so softmax is exp2(s) with no further scaling.
#define QSCALE 0.0450842137604569f

// ---------------------------------------------------------------------------
// x [8192x1024] fp32 -> bf16
// ---------------------------------------------------------------------------
__global__ __launch_bounds__(256) void cvt_x_kernel(const float* __restrict__ x,
                                                    unsigned short* __restrict__ xb)
{
    const int idx = (blockIdx.x * 256 + threadIdx.x) * 4;
    const float4 v = *(const float4*)(x + idx);
    ushort4 o;
    o.x = f2bf(v.x); o.y = f2bf(v.y); o.z = f2bf(v.z); o.w = f2bf(v.w);
    *(ushort4*)(xb + idx) = o;
}

// ---------------------------------------------------------------------------
// W [K][N] fp32 -> Wt [N][K] bf16 (transpose), 4 matrices via grid.z
// ---------------------------------------------------------------------------
__global__ __launch_bounds__(256) void cvt_w_kernel(
    const float* __restrict__ w0, const float* __restrict__ w1,
    const float* __restrict__ w2, const float* __restrict__ w3,
    unsigned short* __restrict__ o0, unsigned short* __restrict__ o1,
    unsigned short* __restrict__ o2, unsigned short* __restrict__ o3)
{
    const int z = blockIdx.z;
    const float* W = z == 0 ? w0 : (z == 1 ? w1 : (z == 2 ? w2 : w3));
    unsigned short* O = z == 0 ? o0 : (z == 1 ? o1 : (z == 2 ? o2 : o3));

    __shared__ float Ws[64][65];
    const int t  = threadIdx.x;
    const int k0 = blockIdx.x * 64, n0 = blockIdx.y * 64;
#pragma unroll
    for (int p = 0; p < 4; ++p) {
        const int row = p * 16 + (t >> 4);
        const int col = (t & 15) * 4;
        const float4 v = *(const float4*)(W + (size_t)(k0 + row) * EMB + n0 + col);
        Ws[row][col]     = v.x; Ws[row][col + 1] = v.y;
        Ws[row][col + 2] = v.z; Ws[row][col + 3] = v.w;
    }
    __syncthreads();
    const int nn = t >> 2;
    const int kb = (t & 3) * 16;
#pragma unroll
    for (int q = 0; q < 2; ++q) {
        const int kk = kb + q * 8;
        ushort4 u0, u1;
        u0.x = f2bf(Ws[kk + 0][nn]); u0.y = f2bf(Ws[kk + 1][nn]);
        u0.z = f2bf(Ws[kk + 2][nn]); u0.w = f2bf(Ws[kk + 3][nn]);
        u1.x = f2bf(Ws[kk + 4][nn]); u1.y = f2bf(Ws[kk + 5][nn]);
        u1.z = f2bf(Ws[kk + 6][nn]); u1.w = f2bf(Ws[kk + 7][nn]);
        *(ushort4*)(O + (size_t)(n0 + nn) * EMB + k0 + kk)     = u0;
        *(ushort4*)(O + (size_t)(n0 + nn) * EMB + k0 + kk + 4) = u1;
    }
}

// ---------------------------------------------------------------------------
// bf16 MFMA GEMM, A/B-swapped epilogue (lane holds 4 consecutive e).
// LDS staging XOR-swizzled on the GLOBAL side: global chunk =
// (lane&3)^((lane>>3)&3); frag reads un-swizzle with quad^((row>>1)&3) —
// spreads the 16 frag-read lanes over all 8 bank-groups (2-way = free,
// was 8-way with linear layout: 6.3e6 conflict cycles in round 5).
// mode 0: z= Q/K/V. Q -> [B,H,N,D]*QSCALE; K -> [B,H,N,D];
//         V -> [B,H,D,N], kv permuted per 64-block: np = (n%16)*4 + (n/16)%4,
//         stored as 16 ushort4 (np-consecutive across j-subtiles).
// mode 1: fp32 out [M][E].
// ---------------------------------------------------------------------------
__global__ __launch_bounds__(256) void gemm_bf16_kernel(
    const unsigned short* __restrict__ Ag,
    const unsigned short* __restrict__ B0, const unsigned short* __restrict__ B1,
    const unsigned short* __restrict__ B2,
    const float* __restrict__ bias0, const float* __restrict__ bias1,
    const float* __restrict__ bias2,
    void* out0, void* out1, void* out2, int mode)
{
    const int z = blockIdx.z;
    const unsigned short* __restrict__ Bg = z == 0 ? B0 : (z == 1 ? B1 : B2);
    const float* __restrict__ bias = z == 0 ? bias0 : (z == 1 ? bias1 : bias2);
    void* outp = z == 0 ? out0 : (z == 1 ? out1 : out2);

    __shared__ unsigned short As[128][32];   // x rows   (chunk-swizzled)
    __shared__ unsigned short Bs[128][32];   // W rows   (chunk-swizzled)

    const int t    = threadIdx.x;
    const int w    = t >> 6;
    const int lane = t & 63;
    const int low4 = lane & 15;
    const int quad = lane >> 4;
    const int m0 = blockIdx.x * 128;
    const int e0 = blockIdx.y * 128;
    const int we = (w & 1) * 64;     // e-offset of this wave
    const int wm = (w >> 1) * 64;    // m-offset of this wave

    const int srow   = w * 32 + (lane >> 2);
    // global-side chunk swizzle: h(row) = (row>>1)&3, row-rel = lane>>2
    const int schunk = (lane & 3) ^ ((lane >> 3) & 3);
    const int scol   = schunk * 8;

    // frag-read un-swizzle: chunk = quad ^ ((low4>>1)&3)
    const int fchunk = (quad ^ ((low4 >> 1) & 3)) * 8;

    fx4 acc[4][4] = {};   // [i: e-subtile][j: m-subtile]

    for (int k0 = 0; k0 < EMB; k0 += 32) {
        __syncthreads();
        glds16(Ag + (size_t)(m0 + srow) * EMB + k0 + scol,      &As[w * 32][0]);
        glds16(Ag + (size_t)(m0 + srow + 16) * EMB + k0 + scol, &As[w * 32 + 16][0]);
        glds16(Bg + (size_t)(e0 + srow) * EMB + k0 + scol,      &Bs[w * 32][0]);
        glds16(Bg + (size_t)(e0 + srow + 16) * EMB + k0 + scol, &Bs[w * 32 + 16][0]);
        DRAIN_GLDS();
        __syncthreads();

        bf16x8 af[4], bfr[4];
#pragma unroll
        for (int i = 0; i < 4; ++i) {
            af[i]  = *(const bf16x8*)&Bs[we + i * 16 + low4][fchunk];  // A = W
            bfr[i] = *(const bf16x8*)&As[wm + i * 16 + low4][fchunk];  // B = x
        }
#pragma unroll
        for (int i = 0; i < 4; ++i)
#pragma unroll
            for (int j = 0; j < 4; ++j)
                acc[i][j] = __builtin_amdgcn_mfma_f32_16x16x32_bf16(af[i], bfr[j], acc[i][j], 0, 0, 0);
    }

    // bias: e = e0 + we + i*16 + quad*4 + rr  (4 consecutive)
    fx4 bv[4];
#pragma unroll
    for (int i = 0; i < 4; ++i)
        bv[i] = *(const fx4*)(bias + e0 + we + i * 16 + quad * 4);

    if (mode == 1) {
#pragma unroll
        for (int i = 0; i < 4; ++i)
#pragma unroll
            for (int j = 0; j < 4; ++j) {
                const int m  = m0 + wm + j * 16 + low4;
                const int eb = e0 + we + i * 16 + quad * 4;
                fx4 o4;
#pragma unroll
                for (int rr = 0; rr < 4; ++rr) o4[rr] = acc[i][j][rr] + bv[i][rr];
                *(fx4*)((float*)outp + (size_t)m * EMB + eb) = o4;
            }
    } else if (z <= 1) {
        const float sc = (z == 0) ? QSCALE : 1.0f;
        unsigned short* o = (unsigned short*)outp;
#pragma unroll
        for (int i = 0; i < 4; ++i)
#pragma unroll
            for (int j = 0; j < 4; ++j) {
                const int m  = m0 + wm + j * 16 + low4;
                const int eb = e0 + we + i * 16 + quad * 4;
                const int bb = m >> 11, n = m & (SEQ - 1);
                const int hh = eb >> 6, db = eb & 63;
                ushort4 o4;
                o4.x = f2bf((acc[i][j][0] + bv[i][0]) * sc);
                o4.y = f2bf((acc[i][j][1] + bv[i][1]) * sc);
                o4.z = f2bf((acc[i][j][2] + bv[i][2]) * sc);
                o4.w = f2bf((acc[i][j][3] + bv[i][3]) * sc);
                *(ushort4*)(o + (((size_t)(bb * HEADS + hh)) * SEQ + n) * HDIM + db) = o4;
            }
    } else {
        // V: for fixed (lane, rr) the four j-subtiles give the 4 consecutive
        // permuted columns np = low4*4 + j  ->  one ushort4 per (i, rr).
        unsigned short* o = (unsigned short*)outp;
        const int mbase = m0 + wm;                  // multiple of 64
        const int bb    = mbase >> 11;
        const int nb    = mbase & (SEQ - 1);        // 64-aligned block base
#pragma unroll
        for (int i = 0; i < 4; ++i) {
            const int eb = e0 + we + i * 16 + quad * 4;
            const int hh = eb >> 6, db = eb & 63;
#pragma unroll
            for (int rr = 0; rr < 4; ++rr) {
                ushort4 o4;
                o4.x = f2bf(acc[i][0][rr] + bv[i][rr]);
                o4.y = f2bf(acc[i][1][rr] + bv[i][rr]);
                o4.z = f2bf(acc[i][2][rr] + bv[i][rr]);
                o4.w = f2bf(acc[i][3][rr] + bv[i][rr]);
                *(ushort4*)(o + (((size_t)(bb * HEADS + hh)) * HDIM + db + rr) * SEQ
                              + nb + low4 * 4) = o4;
            }
        }
    }
}

// ---------------------------------------------------------------------------
// MFMA flash attention v4: per-s-subtile Ps slices (breaks the in-order-DS
// false dependency that serialized the 4 S->exp->P->PV chains), LDS-staged
// K/V (glds16, double-buffered, explicit vmcnt drain + barrier), XOR chunk
// swizzle, no-max softmax (exp2, scale folded into Q).
// Wave = 64 q-rows; block = 4 waves = 256 q-rows. Grid (SEQ/256, B*H).
// Q,K: [B,H,N,D] bf16; V: [B,H,D,N] bf16 (kv permuted per 64-block).
// ---------------------------------------------------------------------------
__global__ __launch_bounds__(256, 2) void attn_mfma4_kernel(
    const unsigned short* __restrict__ qg, const unsigned short* __restrict__ kg,
    const unsigned short* __restrict__ vg, unsigned short* __restrict__ attb)
{
    __shared__ unsigned short Ks[2][64][64];      // [buf][kv][d], chunk-swizzled
    __shared__ unsigned short Vs[2][64][64];      // [buf][d][kv'], chunk-swizzled
    __shared__ unsigned short Ps[4][4][16][72];   // [wave][s][q][kv'] — private per s

    const int t    = threadIdx.x;
    const int w    = t >> 6;
    const int lane = t & 63;
    const int low4 = lane & 15;
    const int quad = lane >> 4;
    const int q0   = blockIdx.x * 256 + w * 64;
    const int bh   = blockIdx.y;
    const size_t base = (size_t)bh * SEQ * HDIM;

    // staging source (XOR swizzle): lane covers row srow8, global chunk schunk
    const int srow8  = lane >> 3;                    // 0..7 within 8-row group
    const int schunk = (lane & 7) ^ srow8;           // swizzled 16B chunk

    // resident Q A-fragments: 4 sub-tiles of 16 q-rows
    bf16x8 aq[4][2];
#pragma unroll
    for (int s = 0; s < 4; ++s) {
        const size_t qrow = base + (size_t)(q0 + s * 16 + low4) * HDIM;
        aq[s][0] = *(const bf16x8*)(qg + qrow + quad * 8);
        aq[s][1] = *(const bf16x8*)(qg + qrow + 32 + quad * 8);
    }

    fx4 o_acc[4][4] = {};
    float l_i[4][4] = {};
    const fx4 fzero = {0.f, 0.f, 0.f, 0.f};

    // prologue: stage tile 0 into buf 0
    {
        const unsigned short* kp = kg + base + (size_t)(w * 16 + srow8) * HDIM + schunk * 8;
        glds16(kp,              &Ks[0][w * 16][0]);
        glds16(kp + 8 * HDIM,   &Ks[0][w * 16 + 8][0]);
        const unsigned short* vp = vg + base + (size_t)(w * 16 + srow8) * SEQ + schunk * 8;
        glds16(vp,              &Vs[0][w * 16][0]);
        glds16(vp + 8 * SEQ,    &Vs[0][w * 16 + 8][0]);
    }

    for (int tt0 = 0; tt0 < SEQ / 64; ++tt0) {
        const int buf = tt0 & 1;
        DRAIN_GLDS();      // drain this wave's in-flight glds (round-4 fix)
        __syncthreads();   // rendezvous: all waves' DMA data now in LDS

        // K/V fragments -> registers (unswizzle: lds chunk = cg ^ (row&7))
        bf16x8 kf[4][2], vf[4][2];
#pragma unroll
        for (int tk = 0; tk < 4; ++tk) {
            const int row = tk * 16 + low4;
            const int x7  = low4 & 7;
#pragma unroll
            for (int c = 0; c < 2; ++c) {
                const int lc = (c * 4 + quad) ^ x7;
                kf[tk][c] = *(const bf16x8*)&Ks[buf][row][lc * 8];
                vf[tk][c] = *(const bf16x8*)&Vs[buf][row][lc * 8];
            }
        }

        // prefetch next tile into other buffer (overlaps compute below)
        if (tt0 + 1 < SEQ / 64) {
            const int kv1 = (tt0 + 1) * 64;
            const unsigned short* kp = kg + base + (size_t)(kv1 + w * 16 + srow8) * HDIM + schunk * 8;
            glds16(kp,            &Ks[buf ^ 1][w * 16][0]);
            glds16(kp + 8 * HDIM, &Ks[buf ^ 1][w * 16 + 8][0]);
            const unsigned short* vp = vg + base + (size_t)(w * 16 + srow8) * SEQ + kv1 + schunk * 8;
            glds16(vp,            &Vs[buf ^ 1][w * 16][0]);
            glds16(vp + 8 * SEQ,  &Vs[buf ^ 1][w * 16 + 8][0]);
        }

#pragma unroll
        for (int s = 0; s < 4; ++s) {
            // S = Q K^T
            fx4 sa[4];
#pragma unroll
            for (int tk = 0; tk < 4; ++tk) {
                sa[tk] = __builtin_amdgcn_mfma_f32_16x16x32_bf16(aq[s][0], kf[tk][0], fzero, 0, 0, 0);
                sa[tk] = __builtin_amdgcn_mfma_f32_16x16x32_bf16(aq[s][1], kf[tk][1], sa[tk], 0, 0, 0);
            }
            // P = exp2(S); store to the s-private Ps slice
#pragma unroll
            for (int r = 0; r < 4; ++r) {
                const float p0 = EXP2(sa[0][r]);
                const float p1 = EXP2(sa[1][r]);
                const float p2 = EXP2(sa[2][r]);
                const float p3 = EXP2(sa[3][r]);
                l_i[s][r] += (p0 + p1) + (p2 + p3);
                uint2 pk;
                pk.x = (unsigned)bfbits(p0) | ((unsigned)bfbits(p1) << 16);
                pk.y = (unsigned)bfbits(p2) | ((unsigned)bfbits(p3) << 16);
                *(uint2*)&Ps[w][s][quad * 4 + r][low4 * 4] = pk;
            }
            // O += P V  (intra-wave LDS ordering; s-slices independent)
            bf16x8 pf0 = *(const bf16x8*)&Ps[w][s][low4][quad * 8];
            bf16x8 pf1 = *(const bf16x8*)&Ps[w][s][low4][32 + quad * 8];
#pragma unroll
            for (int t2 = 0; t2 < 4; ++t2) {
                o_acc[s][t2] = __builtin_amdgcn_mfma_f32_16x16x32_bf16(pf0, vf[t2][0], o_acc[s][t2], 0, 0, 0);
                o_acc[s][t2] = __builtin_amdgcn_mfma_f32_16x16x32_bf16(pf1, vf[t2][1], o_acc[s][t2], 0, 0, 0);
            }
        }
    }

    // final l reduction across the 16 lanes of each quad-row group
#pragma unroll
    for (int s = 0; s < 4; ++s)
#pragma unroll
        for (int r = 0; r < 4; ++r) {
            float v = l_i[s][r];
            for (int off = 1; off < 16; off <<= 1)
                v += __shfl_xor(v, off, 16);
            l_i[s][r] = 1.0f / v;
        }

    // epilogue: merge heads -> att [B*N][EMB] bf16
    const int bb = bh >> 4, hh = bh & 15;
#pragma unroll
    for (int s = 0; s < 4; ++s)
#pragma unroll
        for (int r = 0; r < 4; ++r) {
            const size_t m = (size_t)bb * SEQ + q0 + s * 16 + quad * 4 + r;
#pragma unroll
            for (int t2 = 0; t2 < 4; ++t2) {
                const int e = hh * HDIM + t2 * 16 + low4;
                attb[m * EMB + e] = bfbits(o_acc[s][t2][r] * l_i[s][r]);
            }
        }
}

extern "C" void kernel_launch(void* const* d_in, const int* in_sizes, int n_in,
                              void* d_out, int out_size, void* d_ws, size_t ws_size,
                              hipStream_t stream)
{
    const float* x  = (const float*)d_in[0];
    const float* Wq = (const float*)d_in[1];
    const float* bq = (const float*)d_in[2];
    const float* Wk = (const float*)d_in[3];
    const float* bk = (const float*)d_in[4];
    const float* Wv = (const float*)d_in[5];
    const float* bv = (const float*)d_in[6];
    const float* Wo = (const float*)d_in[7];
    const float* bo = (const float*)d_in[8];

    unsigned short* ws  = (unsigned short*)d_ws;
    unsigned short* xb  = ws;                  // 8388608
    unsigned short* wqt = xb + 8388608;        // 1048576 each
    unsigned short* wkt = wqt + 1048576;
    unsigned short* wvt = wkt + 1048576;
    unsigned short* wot = wvt + 1048576;
    unsigned short* qb  = wot + 1048576;       // 8388608 each
    unsigned short* kbuf = qb + 8388608;
    unsigned short* vtb  = kbuf + 8388608;
    unsigned short* attb = vtb + 8388608;

    cvt_x_kernel<<<8192, 256, 0, stream>>>(x, xb);
    cvt_w_kernel<<<dim3(16, 16, 4), 256, 0, stream>>>(Wq, Wk, Wv, Wo, wqt, wkt, wvt, wot);

    gemm_bf16_kernel<<<dim3(64, 8, 3), 256, 0, stream>>>(
        xb, wqt, wkt, wvt, bq, bk, bv, qb, kbuf, vtb, 0);

    attn_mfma4_kernel<<<dim3(8, 64), 256, 0, stream>>>(qb, kbuf, vtb, attb);

    gemm_bf16_kernel<<<dim3(64, 8, 1), 256, 0, stream>>>(
        attb, wot, wot, wot, bo, bo, bo, d_out, d_out, d_out, 1);
}